// Round 15
// baseline (9533.739 us; speedup 1.0000x reference)
//
#include <hip/hip_runtime.h>
#include <stdint.h>

// DecoderRNN R30: R29 base (7.32ms) + direct-data-spin on the TWO remaining
// critical detects (canary->load serialization removed, ~1 RTT each):
//  - role2 phase B (h0[t] -> gi): the load+validate retry loop IS the
//    detector now (canary deleted). 16KB/WG/iter, s_sleep-paced, addresses
//    distributed across the h0 plane (no per-line concentration = not the
//    R21/R24 failure mode). Tag distinctness across generations verified
//    (h0 reuse period 2: ((t>>1)&1)^1 differs t vs t-2).
//  - role3 (h1[t] -> y): same; canary deleted, 32KB/WG/iter spin.
//  Slack-funded waits keep dual canaries: role0-h0 (peers finish together),
//  role2-A (full step of slack) -- no benefit from spinning, less traffic.
//  role0's y path already direct-spin (R29, proven WIN).
// Everything else byte-identical to R29 (tagged planes, no flags, no
// producer drains, role1 eliminated, role2 x64 4-way K-split, Wih1 hi-only).

#define NWG 256
#define NT  256
#define TT  1024

typedef unsigned short ushort;
typedef unsigned int   uint;
typedef __attribute__((ext_vector_type(8))) short short8;
typedef __attribute__((ext_vector_type(4))) float f32x4;
typedef __attribute__((ext_vector_type(4))) uint  uint4v;

struct __align__(16) SmemR0 {
  ushort wpl[2][48*520];     // Whh0 hi/lo
  float  gictx[3*16*68];
  float  wcol[3][16];
  float  bhnN[16];
  float  prevS[64];          // [0..32) used
};
struct __align__(16) SmemR2 {
  ushort whh[2][48*520];     // Whh1 hi/lo (full precision, self-recurrence)
  ushort wih[48*520];        // Wih1 HI ONLY (critical path)
  float  xk[3][64][16];      // k-quarter combine: {R,Z,Ni,Nh} x4
  float  bsumR[16], bsumZ[16], binN[16], bhnN[16];
};
struct __align__(16) SmemR3 {
  ushort wpl[2][16*520];     // Wo1 block hi/lo
  float  xk[2][64][4];
  float  bo1v[16], wo2v[16];
};

__device__ __forceinline__ float frcp(float x){
#if __has_builtin(__builtin_amdgcn_rcpf)
  return __builtin_amdgcn_rcpf(x);
#else
  return 1.f/x;
#endif
}
__device__ __forceinline__ float sigm(float x){ return frcp(1.f + __expf(-x)); }
__device__ __forceinline__ float tanh_f(float x){
  return 1.f - 2.f*frcp(__expf(2.f*x) + 1.f);
}
__device__ __forceinline__ float bf2f(ushort h){ return __uint_as_float(((uint)h)<<16); }
__device__ __forceinline__ ushort bfrnd(float x){
  uint u = __float_as_uint(x);
  return (ushort)((u + 0x7fffu + ((u>>16)&1u)) >> 16);
}
#define SWP(p, v)  (void)__hip_atomic_exchange((uint*)(p), (uint)(v), __ATOMIC_RELAXED, __HIP_MEMORY_SCOPE_AGENT)
#define ALD1(p)    __hip_atomic_load((const uint*)(p), __ATOMIC_RELAXED, __HIP_MEMORY_SCOPE_AGENT)
#define ALDF(p)    __uint_as_float(ALD1(p))

__device__ __forceinline__ void gbar(int* slots, int* epoch, int w, int tid, int e){
  __syncthreads();
  if (tid == 0)
    __hip_atomic_store(&slots[w], e, __ATOMIC_RELEASE, __HIP_MEMORY_SCOPE_AGENT);
  if (w == 0 && tid < 64){
    for(;;){
      int m0 = __hip_atomic_load(&slots[tid*4+0], __ATOMIC_RELAXED, __HIP_MEMORY_SCOPE_AGENT);
      int m1 = __hip_atomic_load(&slots[tid*4+1], __ATOMIC_RELAXED, __HIP_MEMORY_SCOPE_AGENT);
      int m2 = __hip_atomic_load(&slots[tid*4+2], __ATOMIC_RELAXED, __HIP_MEMORY_SCOPE_AGENT);
      int m3 = __hip_atomic_load(&slots[tid*4+3], __ATOMIC_RELAXED, __HIP_MEMORY_SCOPE_AGENT);
      if (__all(min(min(m0,m1),min(m2,m3)) >= e)) break;
      __builtin_amdgcn_s_sleep(1);
    }
    if (tid == 0){
      __builtin_amdgcn_fence(__ATOMIC_ACQUIRE, "agent");
      __hip_atomic_store(epoch, e, __ATOMIC_RELEASE, __HIP_MEMORY_SCOPE_AGENT);
    }
  }
  if (tid == 0){
    while (__hip_atomic_load(epoch, __ATOMIC_RELAXED, __HIP_MEMORY_SCOPE_AGENT) < e)
      __builtin_amdgcn_s_sleep(1);
    __builtin_amdgcn_fence(__ATOMIC_ACQUIRE, "agent");
  }
  __syncthreads();
}

__device__ __forceinline__ void drain_sync(){
  __builtin_amdgcn_s_waitcnt(0);
  __syncthreads();
}

// coherent LLC-direct ops (sc0 sc1 = bypass L1+L2, coalesced)
#define LD1SCD(dst, addr) \
  asm volatile("global_load_dword %0, %1, off sc0 sc1" : "=v"(dst) : "v"(addr));
#define STSH(addr, val) \
  asm volatile("global_store_short %0, %1, off sc0 sc1" :: "v"(addr), "v"(val) : "memory");
#define ST4SC(addr, val) \
  asm volatile("global_store_dwordx4 %0, %1, off sc0 sc1" :: "v"(addr), "v"(val) : "memory");
#define LD4A(DST, P, OFS) \
  asm volatile("global_load_dwordx4 %0, %1, off sc0 sc1" : "=v"(DST) : "v"((P) + (OFS)));
#define VMBAR2(a,b) asm volatile("s_waitcnt vmcnt(0)" : "+v"(a),"+v"(b));
#define VMBAR4(a,b,c,d) \
  asm volatile("s_waitcnt vmcnt(0)" : "+v"(a),"+v"(b),"+v"(c),"+v"(d));
#define VMBAR8(a,b,c,d,e,f,g,h) \
  asm volatile("s_waitcnt vmcnt(0)" \
               : "+v"(a),"+v"(b),"+v"(c),"+v"(d),"+v"(e),"+v"(f),"+v"(g),"+v"(h));

// ---- tag machinery --------------------------------------------------------
#define TAGM 0x00010001u
#define FOLDV(V) fo_ |= ((V.x^em_)&TAGM)|((V.y^em_)&TAGM)| \
                        ((V.z^em_)&TAGM)|((V.w^em_)&TAGM);
#define FOLD4(p)  FOLDV(p##0) FOLDV(p##1) FOLDV(p##2) FOLDV(p##3)
#define FOLD8(p)  FOLD4(p) FOLDV(p##4) FOLDV(p##5) FOLDV(p##6) FOLDV(p##7)
#define FOLD16(p) FOLD8(p) FOLDV(p##8) FOLDV(p##9) FOLDV(p##10) FOLDV(p##11) \
                  FOLDV(p##12) FOLDV(p##13) FOLDV(p##14) FOLDV(p##15)

// dual canary poll: tid0 loads two 16B sites (distinct lines) per iteration
__device__ __forceinline__ void waitcan2(const ushort* pa, const ushort* pb,
                                         uint em, int tid){
  if (tid == 0){
    for(;;){
      uint4v a, b;
      LD4A(a, (const uint*)pa, 0)
      LD4A(b, (const uint*)pb, 0)
      VMBAR2(a, b)
      uint fo = ((a.x^em)&TAGM)|((a.y^em)&TAGM)|((a.z^em)&TAGM)|((a.w^em)&TAGM)
              | ((b.x^em)&TAGM)|((b.y^em)&TAGM)|((b.z^em)&TAGM)|((b.w^em)&TAGM);
      if (fo == 0u) break;
    }
  }
  __syncthreads();
}

#define MFMA_ __builtin_amdgcn_mfma_f32_16x16x32_bf16

// ---------------- role0: full-K hi/lo (waves 0,1) ----------------
#define DECL_HILO(PH, PL) \
  uint4v ha0,ha1,ha2,ha3,ha4,ha5,ha6,ha7,ha8,ha9,ha10,ha11,ha12,ha13,ha14,ha15; \
  uint4v la0,la1,la2,la3,la4,la5,la6,la7,la8,la9,la10,la11,la12,la13,la14,la15; \
  LD4A(ha0,PH,aoffB+0*32) LD4A(ha1,PH,aoffB+1*32) LD4A(ha2,PH,aoffB+2*32) LD4A(ha3,PH,aoffB+3*32) \
  LD4A(ha4,PH,aoffB+4*32) LD4A(ha5,PH,aoffB+5*32) LD4A(ha6,PH,aoffB+6*32) LD4A(ha7,PH,aoffB+7*32) \
  LD4A(ha8,PH,aoffB+8*32) LD4A(ha9,PH,aoffB+9*32) LD4A(ha10,PH,aoffB+10*32) LD4A(ha11,PH,aoffB+11*32) \
  LD4A(ha12,PH,aoffB+12*32) LD4A(ha13,PH,aoffB+13*32) LD4A(ha14,PH,aoffB+14*32) LD4A(ha15,PH,aoffB+15*32) \
  LD4A(la0,PL,aoffB+0*32) LD4A(la1,PL,aoffB+1*32) LD4A(la2,PL,aoffB+2*32) LD4A(la3,PL,aoffB+3*32) \
  LD4A(la4,PL,aoffB+4*32) LD4A(la5,PL,aoffB+5*32) LD4A(la6,PL,aoffB+6*32) LD4A(la7,PL,aoffB+7*32) \
  LD4A(la8,PL,aoffB+8*32) LD4A(la9,PL,aoffB+9*32) LD4A(la10,PL,aoffB+10*32) LD4A(la11,PL,aoffB+11*32) \
  LD4A(la12,PL,aoffB+12*32) LD4A(la13,PL,aoffB+13*32) LD4A(la14,PL,aoffB+14*32) LD4A(la15,PL,aoffB+15*32) \
  VMBAR8(ha0,ha1,ha2,ha3,ha4,ha5,ha6,ha7) \
  VMBAR8(ha8,ha9,ha10,ha11,ha12,ha13,ha14,ha15) \
  VMBAR8(la0,la1,la2,la3,la4,la5,la6,la7) \
  VMBAR8(la8,la9,la10,la11,la12,la13,la14,la15)

#define MS3F(i) { \
  short8 AH_ = __builtin_bit_cast(short8, ha##i); \
  short8 AL_ = __builtin_bit_cast(short8, la##i); \
  const int ko_ = (i)*32 + q*8; \
  short8 bh_ = *(const short8*)(&S0.wpl[0][(col)*520 + ko_]); \
  short8 bl_ = *(const short8*)(&S0.wpl[1][(col)*520 + ko_]); \
  acc0 = MFMA_(AH_, bh_, acc0, 0,0,0); \
  acc0 = MFMA_(AL_, bh_, acc0, 0,0,0); \
  acc0 = MFMA_(AH_, bl_, acc0, 0,0,0); \
  bh_ = *(const short8*)(&S0.wpl[0][(16+col)*520 + ko_]); \
  bl_ = *(const short8*)(&S0.wpl[1][(16+col)*520 + ko_]); \
  acc1 = MFMA_(AH_, bh_, acc1, 0,0,0); \
  acc1 = MFMA_(AL_, bh_, acc1, 0,0,0); \
  acc1 = MFMA_(AH_, bl_, acc1, 0,0,0); \
  bh_ = *(const short8*)(&S0.wpl[0][(32+col)*520 + ko_]); \
  bl_ = *(const short8*)(&S0.wpl[1][(32+col)*520 + ko_]); \
  acc2 = MFMA_(AH_, bh_, acc2, 0,0,0); \
  acc2 = MFMA_(AL_, bh_, acc2, 0,0,0); \
  acc2 = MFMA_(AH_, bl_, acc2, 0,0,0); }

// ---------------- role2: gh1 full (hi/lo A,B) + gi (hi A, hi B) ----------
#define GH1(i) { \
  short8 AH_ = __builtin_bit_cast(short8, ha##i); \
  short8 AL_ = __builtin_bit_cast(short8, la##i); \
  const int ko_ = kq + (i)*32 + q*8; \
  short8 bh_ = *(const short8*)(&S2.whh[0][(col)*520 + ko_]); \
  short8 bl_ = *(const short8*)(&S2.whh[1][(col)*520 + ko_]); \
  aR = MFMA_(AH_, bh_, aR, 0,0,0); \
  aR = MFMA_(AL_, bh_, aR, 0,0,0); \
  aR = MFMA_(AH_, bl_, aR, 0,0,0); \
  bh_ = *(const short8*)(&S2.whh[0][(16+col)*520 + ko_]); \
  bl_ = *(const short8*)(&S2.whh[1][(16+col)*520 + ko_]); \
  aZ = MFMA_(AH_, bh_, aZ, 0,0,0); \
  aZ = MFMA_(AL_, bh_, aZ, 0,0,0); \
  aZ = MFMA_(AH_, bl_, aZ, 0,0,0); \
  bh_ = *(const short8*)(&S2.whh[0][(32+col)*520 + ko_]); \
  bl_ = *(const short8*)(&S2.whh[1][(32+col)*520 + ko_]); \
  aNh = MFMA_(AH_, bh_, aNh, 0,0,0); \
  aNh = MFMA_(AL_, bh_, aNh, 0,0,0); \
  aNh = MFMA_(AH_, bl_, aNh, 0,0,0); }

#define GI1(i) { \
  short8 AH_ = __builtin_bit_cast(short8, ga##i); \
  const int ko_ = kq + (i)*32 + q*8; \
  short8 bh_ = *(const short8*)(&S2.wih[(col)*520 + ko_]); \
  aR = MFMA_(AH_, bh_, aR, 0,0,0); \
  bh_ = *(const short8*)(&S2.wih[(16+col)*520 + ko_]); \
  aZ = MFMA_(AH_, bh_, aZ, 0,0,0); \
  bh_ = *(const short8*)(&S2.wih[(32+col)*520 + ko_]); \
  aNi = MFMA_(AH_, bh_, aNi, 0,0,0); }

// ---------------- role3: k-half hi A, hi/lo B -----------------------------
#define DECL_HI8(P) \
  uint4v ha0,ha1,ha2,ha3,ha4,ha5,ha6,ha7; \
  LD4A(ha0,P,aoff8+0*32) LD4A(ha1,P,aoff8+1*32) LD4A(ha2,P,aoff8+2*32) LD4A(ha3,P,aoff8+3*32) \
  LD4A(ha4,P,aoff8+4*32) LD4A(ha5,P,aoff8+5*32) LD4A(ha6,P,aoff8+6*32) LD4A(ha7,P,aoff8+7*32) \
  VMBAR8(ha0,ha1,ha2,ha3,ha4,ha5,ha6,ha7)

#define MS1H(i) { \
  short8 AH_ = __builtin_bit_cast(short8, ha##i); \
  const int ko_ = kb + (i)*32 + q*8; \
  short8 bh_ = *(const short8*)(&S3.wpl[0][(col)*520 + ko_]); \
  short8 bl_ = *(const short8*)(&S3.wpl[1][(col)*520 + ko_]); \
  acc0 = MFMA_(AH_, bh_, acc0, 0,0,0); \
  acc0 = MFMA_(AH_, bl_, acc0, 0,0,0); }

#define RUN16(M) M(0) M(1) M(2) M(3) M(4) M(5) M(6) M(7) \
                 M(8) M(9) M(10) M(11) M(12) M(13) M(14) M(15)
#define RUN8(M)  M(0) M(1) M(2) M(3) M(4) M(5) M(6) M(7)
#define RUN4(M)  M(0) M(1) M(2) M(3)

extern "C" __global__ void __launch_bounds__(NT, 1)
decoder_rnn(const float* __restrict__ ctx,   // [64][512]
            const float* __restrict__ Wih0,  // [1536][513] (row stride 513!)
            const float* __restrict__ Whh0,
            const float* __restrict__ bih0,
            const float* __restrict__ bhh0g,
            const float* __restrict__ Wih1,
            const float* __restrict__ Whh1,
            const float* __restrict__ bih1g,
            const float* __restrict__ bhh1g,
            const float* __restrict__ Wo1,
            const float* __restrict__ bo1g,
            const float* __restrict__ Wo2,
            const float* __restrict__ bo2g,
            float* __restrict__ out,         // [64*1024 y][65536 h_i]
            float* __restrict__ ws)
{
  extern __shared__ char smem_raw[];
  SmemR0& S0 = *reinterpret_cast<SmemR0*>(smem_raw);
  SmemR2& S2 = *reinterpret_cast<SmemR2*>(smem_raw);
  SmemR3& S3 = *reinterpret_cast<SmemR3*>(smem_raw);
  const int tid = threadIdx.x;
  const int wg  = blockIdx.x;

  ushort* hp  = (ushort*)ws;                 // h0hi[2]@0/32768, h0lo[2]@65536/
                                             // 98304, h1hi@131072, h1lo@163840
  float* yout = (float*)ws + 196608;         // 2 x 2048
  int*  ibase = (int*)((float*)ws + 200704);
  int* gslots = ibase;                       // [256] gbar
  int* epoch  = ibase + 256;

  const float bo2v = bo2g[0];

  // ---------------- init (swaps -> LLC; once, off critical path) ----------
  for (int i = wg*NT + tid; i < 200704; i += NWG*NT)
    SWP((uint*)ws + i, 0u);

  const int gid   = wg >> 7;                 // 2 independent 32-batch machines
  const int m     = wg & 127;
  const int bbase = 32*gid;
  int role, j, bh = 0;
  if (m < 32){ role = 0; j = m; }
  else if (m < 96){ role = 2; bh = (m - 32) >> 5; j = m & 31; }
  else { role = 3; j = m - 96; }

  if (role == 0){
    for (int i = tid; i < 48*512; i += NT){
      int r = i >> 9, k = i & 511;
      int g3 = r >> 4, n = r & 15;
      float wv = Whh0[(size_t)(g3*512 + 16*j + n)*512 + k];
      ushort hh = bfrnd(wv);
      S0.wpl[0][r*520 + k] = hh;
      S0.wpl[1][r*520 + k] = bfrnd(wv - bf2f(hh));
    }
    if (tid < 48){
      int g3 = tid >> 4, n = tid & 15;
      S0.wcol[g3][n] = Wih0[(size_t)(g3*512 + 16*j + n)*513 + 512];
    }
    if (tid < 16) S0.bhnN[tid] = bhh0g[2*512 + 16*j + tid];
    for (int idx = tid; idx < 1536; idx += NT){   // 48 rows x 32 local b
      int r = idx >> 5, bl = idx & 31;
      int g3 = r >> 4, n = r & 15;
      int grow = g3*512 + 16*j + n;
      const float* wr = Wih0 + (size_t)grow*513;
      const float* cx = ctx  + (size_t)(bbase + bl)*512;
      float s = bih0[grow];
      if (g3 < 2) s += bhh0g[grow];
      #pragma unroll 4
      for (int k = 0; k < 512; ++k) s += wr[k]*cx[k];
      S0.gictx[g3*1088 + n*68 + bl] = s;
    }
  } else if (role == 2){
    for (int i = tid; i < 48*512; i += NT){
      int r = i >> 9, k = i & 511;
      int g3 = r >> 4, n = r & 15;
      size_t row = (size_t)(g3*512 + 16*j + n)*512 + k;
      float wv = Whh1[row];
      ushort hh = bfrnd(wv);
      S2.whh[0][r*520 + k] = hh;
      S2.whh[1][r*520 + k] = bfrnd(wv - bf2f(hh));
      S2.wih[r*520 + k] = bfrnd(Wih1[row]);       // HI ONLY
    }
    if (tid < 16){
      int n = tid;
      S2.bsumR[n] = bih1g[16*j + n]       + bhh1g[16*j + n];
      S2.bsumZ[n] = bih1g[512 + 16*j + n] + bhh1g[512 + 16*j + n];
      S2.binN[n]  = bih1g[1024 + 16*j + n];
      S2.bhnN[n]  = bhh1g[1024 + 16*j + n];
    }
  } else {
    for (int i = tid; i < 16*512; i += NT){
      int r = i >> 9, k = i & 511;
      float wv = Wo1[(size_t)(16*j + r)*512 + k];
      ushort hh = bfrnd(wv);
      S3.wpl[0][r*520 + k] = hh;
      S3.wpl[1][r*520 + k] = bfrnd(wv - bf2f(hh));
    }
    if (tid < 16){ S3.bo1v[tid] = bo1g[16*j + tid]; S3.wo2v[tid] = Wo2[16*j + tid]; }
  }

  gbar(gslots, epoch, wg, tid, 1);

  const int v   = tid >> 6;
  const int l   = tid & 63;
  const int q   = l >> 4;
  const int col = l & 15;
  const int ng  = 16*j + col;

  if (role == 0){
    const int bblk  = v & 1;
    const int aoffB = (bbase + 16*bblk + col)*512 + q*8;
    const int b0wL  = 16*bblk + 4*q;
    float hc0 = 0.f, hc1 = 0.f, hc2 = 0.f, hc3 = 0.f;
    for (int t = 0; t < TT; ++t){
      const int r0 = t & 1, w0 = r0 ^ 1;
      const ushort* rH = hp + r0*32768;
      const ushort* rL = hp + 65536 + r0*32768;
      ushort*       wH = hp + w0*32768;
      ushort*       wL = hp + 65536 + w0*32768;
      const uint emh = (t==0) ? 0u : (((((t-1)>>1)&1u)^1u) * TAGM);
      // dual canary (slack wait: peers finish ~together)
      waitcan2(rH + (size_t)bbase*512, rH + (size_t)bbase*512 + 496, emh, tid);
      f32x4 acc0={0,0,0,0}, acc1={0,0,0,0}, acc2={0,0,0,0};
      if (v < 2){
        const uint em_ = emh;
        for(;;){
          DECL_HILO(rH, rL)
          uint fo_ = 0u;
          FOLD16(ha) FOLD16(la)
          if (__all((int)(fo_ == 0u))){ RUN16(MS3F) break; }
          __builtin_amdgcn_s_sleep(1);
        }
      }
      if (v == 2){                           // y path: spin ON the data (R29)
        float s = 0.f;
        if (t > 0){
          const uint ey_ = (((t-1)>>1)&1u)^1u;
          const float* yp = yout + ((t-1)&1)*2048 + bbase + l;
          for(;;){
            float vv[32]; uint fo_ = 0u;
            if (l < 32){
              #pragma unroll
              for (int jj = 0; jj < 32; ++jj)
                LD1SCD(vv[jj], yp + jj*64)
              VMBAR8(vv[0],vv[1],vv[2],vv[3],vv[4],vv[5],vv[6],vv[7])
              VMBAR8(vv[8],vv[9],vv[10],vv[11],vv[12],vv[13],vv[14],vv[15])
              VMBAR8(vv[16],vv[17],vv[18],vv[19],vv[20],vv[21],vv[22],vv[23])
              VMBAR8(vv[24],vv[25],vv[26],vv[27],vv[28],vv[29],vv[30],vv[31])
              #pragma unroll
              for (int jj = 0; jj < 32; ++jj)
                fo_ |= (__float_as_uint(vv[jj]) ^ ey_) & 1u;
            }
            if (__all((int)(fo_ == 0u))){
              if (l < 32){
                #pragma unroll
                for (int st = 16; st >= 1; st >>= 1)
                  #pragma unroll
                  for (int k2 = 0; k2 < st; ++k2) vv[k2] += vv[k2 + st];
                s = vv[0];
              }
              break;
            }
            __builtin_amdgcn_s_sleep(1);
          }
        }
        if (l < 32){
          float pv = fmaxf(s + bo2v, 0.f);
          S0.prevS[l] = pv;
          if (j == 0 && t > 0) out[(size_t)(bbase + l)*TT + (t-1)] = pv;
        }
      }
      __syncthreads();
      if (v < 2){
        const uint tg0_ = ((t>>1)&1u)^1u;
        f32x4 pv4 = *(const f32x4*)&S0.prevS[b0wL];
        f32x4 gR = *(const f32x4*)&S0.gictx[0*1088 + col*68 + b0wL];
        f32x4 gZ = *(const f32x4*)&S0.gictx[1*1088 + col*68 + b0wL];
        f32x4 gN = *(const f32x4*)&S0.gictx[2*1088 + col*68 + b0wL];
        float wc0 = S0.wcol[0][col], wc1 = S0.wcol[1][col], wc2 = S0.wcol[2][col];
        float bhn = S0.bhnN[col];
        #define E0(i, HC) { \
          float rr = sigm(gR[i] + pv4[i]*wc0 + acc0[i]); \
          float zz = sigm(gZ[i] + pv4[i]*wc1 + acc1[i]); \
          float nn = tanh_f(gN[i] + pv4[i]*wc2 + rr*(acc2[i] + bhn)); \
          float h = (1.f-zz)*nn + zz*HC; \
          HC = h; \
          uint hu_ = ((uint)bfrnd(h) & 0xFFFEu) | tg0_; \
          uint lu_ = ((uint)bfrnd(h - bf2f((ushort)hu_)) & 0xFFFEu) | tg0_; \
          STSH(wH + (size_t)(bbase + b0wL + (i))*512 + ng, hu_) \
          STSH(wL + (size_t)(bbase + b0wL + (i))*512 + ng, lu_) }
        E0(0,hc0) E0(1,hc1) E0(2,hc2) E0(3,hc3)
        #undef E0
      }
      // stores issued; consumers detect via data tags (no flag, no drain)
    }
  } else if (role == 2){
    ushort* p1H = hp + 131072;
    ushort* p1L = hp + 163840;
    const int bb16  = bbase + 16*bh;
    const int kq    = v*128;                 // k-quarter per wave
    const int aoffA = (bb16 + col)*512 + kq + q*8;
    float hc0 = 0.f, hc1 = 0.f, hc2 = 0.f, hc3 = 0.f;   // wave0: batches 4q+i
    for (int t = 0; t < TT; ++t){
      // -------- phase A (slack-funded): gh1 = Whh1 @ h1[t-1], full prec ----
      const uint emA = (t==0) ? 0u : ((((t-1)&1u)^1u) * TAGM);
      waitcan2(p1H + (size_t)bb16*512, p1H + (size_t)bb16*512 + 496, emA, tid);
      f32x4 aR={0,0,0,0}, aZ={0,0,0,0}, aNi={0,0,0,0}, aNh={0,0,0,0};
      {
        const uint em_ = emA;
        for(;;){
          uint4v ha0,ha1,ha2,ha3, la0,la1,la2,la3;
          LD4A(ha0, p1H, aoffA+0*32) LD4A(ha1, p1H, aoffA+1*32)
          LD4A(ha2, p1H, aoffA+2*32) LD4A(ha3, p1H, aoffA+3*32)
          LD4A(la0, p1L, aoffA+0*32) LD4A(la1, p1L, aoffA+1*32)
          LD4A(la2, p1L, aoffA+2*32) LD4A(la3, p1L, aoffA+3*32)
          VMBAR8(ha0,ha1,ha2,ha3,la0,la1,la2,la3)
          uint fo_ = 0u;
          FOLD4(ha) FOLD4(la)
          if (__all((int)(fo_ == 0u))){ RUN4(GH1) break; }
          __builtin_amdgcn_s_sleep(1);
        }
      }
      // -------- phase B (critical): DIRECT DATA-SPIN on h0[t] -------------
      const ushort* rH = hp + ((t & 1) ^ 1)*32768;
      {
        const uint em_ = (((t>>1)&1u)^1u) * TAGM;
        for(;;){
          uint4v ga0,ga1,ga2,ga3;
          LD4A(ga0, rH, aoffA+0*32) LD4A(ga1, rH, aoffA+1*32)
          LD4A(ga2, rH, aoffA+2*32) LD4A(ga3, rH, aoffA+3*32)
          VMBAR4(ga0,ga1,ga2,ga3)
          uint fo_ = 0u;
          FOLD4(ga)
          if (__all((int)(fo_ == 0u))){ RUN4(GI1) break; }
          __builtin_amdgcn_s_sleep(1);
        }
      }
      // -------- combine k-quarters, EW, store -----------------------------
      if (v >= 1){
        *(f32x4*)&S2.xk[v-1][l][0]  = aR;
        *(f32x4*)&S2.xk[v-1][l][4]  = aZ;
        *(f32x4*)&S2.xk[v-1][l][8]  = aNi;
        *(f32x4*)&S2.xk[v-1][l][12] = aNh;
      }
      __syncthreads();
      if (v == 0){
        const uint tg1_ = (t&1u)^1u;
        #pragma unroll
        for (int w = 0; w < 3; ++w){
          aR  += *(const f32x4*)&S2.xk[w][l][0];
          aZ  += *(const f32x4*)&S2.xk[w][l][4];
          aNi += *(const f32x4*)&S2.xk[w][l][8];
          aNh += *(const f32x4*)&S2.xk[w][l][12];
        }
        float bsR = S2.bsumR[col], bsZ = S2.bsumZ[col];
        float biN = S2.binN[col],  bhN = S2.bhnN[col];
        #define E1(i, HC) { \
          float r1 = sigm(aR[i] + bsR); \
          float z1 = sigm(aZ[i] + bsZ); \
          float n1 = tanh_f(aNi[i] + biN + r1*(aNh[i] + bhN)); \
          float h = (1.f-z1)*n1 + z1*HC; \
          HC = h; \
          uint hu_ = ((uint)bfrnd(h) & 0xFFFEu) | tg1_; \
          uint lu_ = ((uint)bfrnd(h - bf2f((ushort)hu_)) & 0xFFFEu) | tg1_; \
          STSH(p1H + (size_t)(bb16 + 4*q + (i))*512 + ng, hu_) \
          STSH(p1L + (size_t)(bb16 + 4*q + (i))*512 + ng, lu_) }
        E1(0,hc0) E1(1,hc1) E1(2,hc2) E1(3,hc3)
        #undef E1
      }
      __syncthreads();                       // xk buffer reuse fence
    }
  } else {
    const ushort* rH = hp + 131072;          // h1 hi plane ONLY (critical)
    const int bblk  = v & 1;
    const int kb    = (v >> 1)*256;
    const int aoff8 = (bbase + 16*bblk + col)*512 + kb + q*8;
    const int b0wL  = 16*bblk + 4*q;
    for (int t = 0; t < TT; ++t){
      // -------- DIRECT DATA-SPIN on h1[t] (canary removed) ----------------
      f32x4 acc0={0,0,0,0};
      {
        const uint em_ = ((t&1u)^1u) * TAGM;
        for(;;){
          DECL_HI8(rH)
          uint fo_ = 0u;
          FOLD8(ha)
          if (__all((int)(fo_ == 0u))){ RUN8(MS1H) break; }
          __builtin_amdgcn_s_sleep(1);
        }
      }
      if (v >= 2)
        *(f32x4*)&S3.xk[bblk][l][0] = acc0;
      __syncthreads();
      if (v < 2){
        acc0 += *(const f32x4*)&S3.xk[bblk][l][0];
        float s0 = S3.wo2v[col]*fmaxf(acc0[0] + S3.bo1v[col], 0.f);
        float s1 = S3.wo2v[col]*fmaxf(acc0[1] + S3.bo1v[col], 0.f);
        float s2 = S3.wo2v[col]*fmaxf(acc0[2] + S3.bo1v[col], 0.f);
        float s3 = S3.wo2v[col]*fmaxf(acc0[3] + S3.bo1v[col], 0.f);
        #pragma unroll
        for (int d = 1; d < 16; d <<= 1){
          s0 += __shfl_xor(s0, d);
          s1 += __shfl_xor(s1, d);
          s2 += __shfl_xor(s2, d);
          s3 += __shfl_xor(s3, d);
        }
        if (col == 0){
          const uint tgy_ = ((t>>1)&1u)^1u;
          uint* rp = (uint*)(yout + (t&1)*2048 + j*64 + bbase + b0wL);
          uint4v uv = { (__float_as_uint(s0) & ~1u) | tgy_,
                        (__float_as_uint(s1) & ~1u) | tgy_,
                        (__float_as_uint(s2) & ~1u) | tgy_,
                        (__float_as_uint(s3) & ~1u) | tgy_ };
          ST4SC(rp, uv)
        }
      }
      __syncthreads();                       // xk buffer reuse fence
    }
  }

  // ---------------- finale: drain once, then global barrier ---------------
  drain_sync();
  gbar(gslots, epoch, wg, tid, 2);
  if (wg == 0 && tid < 64){
    float s = 0.f;
    const float* yp = yout + 2048 + tid;     // parity of t=1023 is 1
    #pragma unroll
    for (int jj = 0; jj < 32; ++jj) s += ALDF(yp + jj*64);
    out[(size_t)tid*TT + 1023] = fmaxf(s + bo2v, 0.f);
  }
  {
    int g = wg*256 + tid;                    // 256 WGs x 256 thr = 65536
    if (g < 32768) out[65536 + g] = bf2f(hp[g]) + bf2f(hp[65536 + g]);
    else {
      int g2 = g - 32768;
      out[65536 + g] = bf2f(hp[131072 + g2]) + bf2f(hp[163840 + g2]);
    }
  }
}

extern "C" void kernel_launch(void* const* d_in, const int* in_sizes, int n_in,
                              void* d_out, int out_size, void* d_ws, size_t ws_size,
                              hipStream_t stream){
  const float* ctx   = (const float*)d_in[0];
  const float* Wih0  = (const float*)d_in[2];
  const float* Whh0  = (const float*)d_in[3];
  const float* bih0  = (const float*)d_in[4];
  const float* bhh0  = (const float*)d_in[5];
  const float* Wih1  = (const float*)d_in[6];
  const float* Whh1  = (const float*)d_in[7];
  const float* bih1  = (const float*)d_in[8];
  const float* bhh1  = (const float*)d_in[9];
  const float* Wo1   = (const float*)d_in[10];
  const float* bo1   = (const float*)d_in[11];
  const float* Wo2   = (const float*)d_in[12];
  const float* bo2   = (const float*)d_in[13];

  (void)in_sizes; (void)n_in; (void)out_size; (void)ws_size;

  const int smem_sz = (int)sizeof(SmemR2);   // largest overlay (162,304 B)
  (void)hipFuncSetAttribute((const void*)decoder_rnn,
                            hipFuncAttributeMaxDynamicSharedMemorySize,
                            smem_sz);

  decoder_rnn<<<NWG, NT, smem_sz, stream>>>(
      ctx, Wih0, Whh0, bih0, bhh0, Wih1, Whh1, bih1, bhh1,
      Wo1, bo1, Wo2, bo2, (float*)d_out, (float*)d_ws);
}